// Round 12
// baseline (167.963 us; speedup 1.0000x reference)
//
#include <hip/hip_runtime.h>
#include <hip/hip_bf16.h>

#define BATCH 8192
#define IDIM 256
#define ODIM 256

#define NC 8
#define IPC 32            // i-values per K-chunk
#define THREADS 256
#define RG_TOT 4096       // (2*IDIM*KGRID)/8

typedef __attribute__((ext_vector_type(8))) short short8;
typedef __attribute__((ext_vector_type(4))) float float4v;
typedef __attribute__((ext_vector_type(16))) float float16v;
typedef __attribute__((ext_vector_type(4))) unsigned int uint4v;

#define INV2PI 0.15915494309189535f

// pack two f32 -> (bf16(c) | bf16(s)<<16), RTNE (prep_w only)
__device__ __forceinline__ unsigned int bf16pack(float c, float s) {
    union { float f; unsigned int u; } a, b;
    a.f = c; b.f = s;
    unsigned int ua = a.u + (0x7fffu + ((a.u >> 16) & 1u));
    unsigned int ub = b.u + (0x7fffu + ((b.u >> 16) & 1u));
    return (ua >> 16) | (ub & 0xffff0000u);
}

// single-instruction pack: lo = bf16(c), hi = bf16(s)
__device__ __forceinline__ unsigned int cvtpk(float c, float s) {
    unsigned int r;
    asm("v_cvt_pk_bf16_f32 %0, %1, %2" : "=v"(r) : "v"(c), "v"(s));
    return r;
}

__device__ __forceinline__ float16v mfma(short8 a, uint4v b, float16v c) {
    return __builtin_amdgcn_mfma_f32_32x32x16_bf16(
        a, __builtin_bit_cast(short8, b), c, 0, 0, 0);
}

// W[2][256][256][64] f32 -> Bw2 k-step slab layout:
// [chunk][wn][s=256][g=2][jl=128] 16B-slots; one (chunk,wn,s) slab = 4KB
// contiguous so kan_main stages it with ONE global_load_lds per thread.
__global__ void prep_w(const float4v* __restrict__ W, uint4v* __restrict__ Bw2) {
    int tid = blockIdx.x * 256 + threadIdx.x;   // 1,048,576 threads
    int rg = tid & 4095;
    int j = tid >> 12;
    float4v c4 = W[j * 4096 + rg];
    float4v s4 = W[1048576 + j * 4096 + rg];
    uint4v o;
    o.x = bf16pack(c4.x, s4.x);
    o.y = bf16pack(c4.y, s4.y);
    o.z = bf16pack(c4.z, s4.z);
    o.w = bf16pack(c4.w, s4.w);
    int chunk = rg >> 9, rl = rg & 511, s = rl >> 1, g = rl & 1;
    int wn = j >> 7, jl = j & 127;
    Bw2[((((size_t)(chunk * 2 + wn) * 256 + s) * 2 + g) << 7) + jl] = o;
}

// 4 waves/block, wave tile 64 rows x 128 cols (32x32x16 MFMA, acc 128 AGPR).
// B staged through a 4-slab LDS ring via global_load_lds + counted vmcnt(3)
// + raw s_barrier (no compiler vmcnt(0) drain). A-frags in registers from
// LDS-resident x. Only vmem op in the loop = the stage (exact vmcnt count).
__global__ __launch_bounds__(THREADS, 2) void kan_main(
    const float* __restrict__ x,
    const char* __restrict__ Bw2,
    float* __restrict__ part)
{
    __shared__ __align__(16) uint4v ring[4][256];   // 16 KB: 4 k-step slabs
    __shared__ float xls[IPC][256];                 // 32 KB: x transposed

    const int bx = blockIdx.x;
    const int chunk = bx & 7;          // K-chunk == XCD id (512 blocks)
    const int wn = (bx >> 3) & 1;      // 128-col half
    const int mb = bx >> 4;            // M-block 0..31 (256 rows)
    const int b0 = mb * 256;
    const int i0 = chunk * IPC;
    const int t = threadIdx.x;
    const int lane = t & 63;
    const int wave = t >> 6;           // 0..3 -> 64-row slice
    const int g = lane >> 5;           // k-octet half
    const int l31 = lane & 31;

    // ---- stage x transposed into LDS (prologue, once) ----
    {
        const float4v* xrow = (const float4v*)(x + (size_t)(b0 + t) * IDIM + i0);
        #pragma unroll
        for (int q = 0; q < 8; ++q) {
            float4v v = xrow[q];
            #pragma unroll
            for (int e = 0; e < 4; ++e) xls[q * 4 + e][t] = v[e];
        }
    }
    __syncthreads();   // full drain ONCE (prologue only)

    // ---- B slab streaming: prologue stages slabs 0..3 ----
    const char* gq = Bw2 + (size_t)(chunk * 2 + wn) * 256 * 4096 + (size_t)t * 16;
    char* lds0 = (char*)&ring[0][0] + wave * 1024;   // wave-uniform dest base
    #pragma unroll
    for (int u = 0; u < 4; ++u) {
        __builtin_amdgcn_global_load_lds(
            (const __attribute__((address_space(1))) void*)gq,
            (__attribute__((address_space(3))) void*)(lds0 + u * 4096),
            16, 0, 0);
        gq += 4096;
    }

    const int r0 = wave * 64 + l31;    // rowset 0 (block-local)
    const int r1 = r0 + 32;            // rowset 1
    const float mbase = (float)(4 * g + 1);

    float16v acc[2][4];
    #pragma unroll
    for (int rr = 0; rr < 2; ++rr)
        #pragma unroll
        for (int f = 0; f < 4; ++f) acc[rr][f] = (float16v)(0.0f);

    // ---- trig init for p = 0 ----
    float cI0[4], sI0[4], cI1[4], sI1[4];
    float c80n, s80n, c81n, s81n;
    {
        const float xk0 = xls[0][r0] * INV2PI;
        const float xk1 = xls[0][r1] * INV2PI;
        #pragma unroll
        for (int u = 0; u < 4; ++u) {
            float r = __builtin_amdgcn_fractf(xk0 * (mbase + (float)u));
            cI0[u] = __builtin_amdgcn_cosf(r); sI0[u] = __builtin_amdgcn_sinf(r);
            r = __builtin_amdgcn_fractf(xk1 * (mbase + (float)u));
            cI1[u] = __builtin_amdgcn_cosf(r); sI1[u] = __builtin_amdgcn_sinf(r);
        }
        float tt = __builtin_amdgcn_fractf(8.0f * xk0);
        c80n = __builtin_amdgcn_cosf(tt); s80n = __builtin_amdgcn_sinf(tt);
        tt = __builtin_amdgcn_fractf(8.0f * xk1);
        c81n = __builtin_amdgcn_cosf(tt); s81n = __builtin_amdgcn_sinf(tt);
    }
    float xn0 = xls[1][r0], xn1 = xls[1][r1];

    for (int p = 0; p < IPC; ++p) {
        float c0[4], s0[4], c1[4], s1[4];
        #pragma unroll
        for (int u = 0; u < 4; ++u) {
            c0[u] = cI0[u]; s0[u] = sI0[u];
            c1[u] = cI1[u]; s1[u] = sI1[u];
        }
        const float c80 = c80n, s80 = s80n, c81 = c81n, s81 = s81n;
        if (p + 1 < IPC) {
            // init for p+1: register-only trans ops, scheduler sinks under MFMAs
            const float xk0 = xn0 * INV2PI, xk1 = xn1 * INV2PI;
            #pragma unroll
            for (int u = 0; u < 4; ++u) {
                float r = __builtin_amdgcn_fractf(xk0 * (mbase + (float)u));
                cI0[u] = __builtin_amdgcn_cosf(r); sI0[u] = __builtin_amdgcn_sinf(r);
                r = __builtin_amdgcn_fractf(xk1 * (mbase + (float)u));
                cI1[u] = __builtin_amdgcn_cosf(r); sI1[u] = __builtin_amdgcn_sinf(r);
            }
            float tt = __builtin_amdgcn_fractf(8.0f * xk0);
            c80n = __builtin_amdgcn_cosf(tt); s80n = __builtin_amdgcn_sinf(tt);
            tt = __builtin_amdgcn_fractf(8.0f * xk1);
            c81n = __builtin_amdgcn_cosf(tt); s81n = __builtin_amdgcn_sinf(tt);
            const int p2 = (p + 2 < IPC) ? (p + 2) : (IPC - 1);
            xn0 = xls[p2][r0]; xn1 = xls[p2][r1];
        }
        #pragma unroll
        for (int ks = 0; ks < 8; ++ks) {
            const int slot = ks & 3;   // == (p*8+ks)&3
            // slab s resident iff own stage (issued 4 iters ago) done:
            asm volatile("s_waitcnt vmcnt(3)" ::: "memory");
            asm volatile("s_barrier" ::: "memory");       // all quarters present
            const uint4v* sb = &ring[slot][g * 128 + l31];
            uint4v bf0 = sb[0];
            uint4v bf1 = sb[32];
            uint4v bf2 = sb[64];
            uint4v bf3 = sb[96];
            uint4v w0, w1;
            #pragma unroll
            for (int u = 0; u < 4; ++u) {
                w0[u] = cvtpk(c0[u], s0[u]);
                w1[u] = cvtpk(c1[u], s1[u]);
            }
            short8 a0 = __builtin_bit_cast(short8, w0);
            short8 a1 = __builtin_bit_cast(short8, w1);
            __builtin_amdgcn_s_setprio(1);
            acc[0][0] = mfma(a0, bf0, acc[0][0]);
            acc[1][0] = mfma(a1, bf0, acc[1][0]);
            acc[0][1] = mfma(a0, bf1, acc[0][1]);
            acc[1][1] = mfma(a1, bf1, acc[1][1]);
            acc[0][2] = mfma(a0, bf2, acc[0][2]);
            acc[1][2] = mfma(a1, bf2, acc[1][2]);
            acc[0][3] = mfma(a0, bf3, acc[0][3]);
            acc[1][3] = mfma(a1, bf3, acc[1][3]);
            __builtin_amdgcn_s_setprio(0);
            asm volatile("s_barrier" ::: "memory");       // all reads of slot done
            // stage slab s+4 into the slot just consumed (tail runs <=16KB
            // past the chunk into the part buffer: loaded, never consumed)
            __builtin_amdgcn_global_load_lds(
                (const __attribute__((address_space(1))) void*)gq,
                (__attribute__((address_space(3))) void*)(lds0 + slot * 4096),
                16, 0, 0);
            gq += 4096;
            if (ks < 7) {
                #pragma unroll
                for (int u = 0; u < 4; ++u) {
                    float cn = fmaf(-s0[u], s80, c0[u] * c80);
                    float sn = fmaf( c0[u], s80, s0[u] * c80);
                    c0[u] = cn; s0[u] = sn;
                    cn = fmaf(-s1[u], s81, c1[u] * c81);
                    sn = fmaf( c1[u], s81, s1[u] * c81);
                    c1[u] = cn; s1[u] = sn;
                }
            }
        }
    }

    // drain in-flight LDS-writing loads before exit (next block reuses LDS)
    asm volatile("s_waitcnt vmcnt(0)" ::: "memory");

    // ---- store partials: part[chunk][b][j] ----
    // 32x32 C/D (verified R4..R11): col = lane&31,
    // row = (v&3) + 8*(v>>2) + 4*(lane>>5)
    const int cb = wn * 128 + l31;
    float* pc = part + (size_t)chunk * (BATCH * ODIM);
    #pragma unroll
    for (int rt = 0; rt < 2; ++rt) {
        const int rb = b0 + wave * 64 + rt * 32 + 4 * g;
        #pragma unroll
        for (int f = 0; f < 4; ++f)
            #pragma unroll
            for (int v = 0; v < 16; ++v) {
                int r = rb + (v & 3) + 8 * (v >> 2);
                pc[(size_t)r * ODIM + cb + f * 32] = acc[rt][f][v];
            }
    }
}

__global__ void reduce_bias(const float4v* __restrict__ part,
                            const float4v* __restrict__ bias,
                            float4v* __restrict__ out)
{
    const int tid = blockIdx.x * 256 + threadIdx.x;   // 524288 float4s
    const int Q = BATCH * ODIM / 4;
    float4v r = part[tid];
    #pragma unroll
    for (int c = 1; c < NC; ++c) r += part[tid + c * Q];
    r += bias[tid & 63];
    out[tid] = r;
}

extern "C" void kernel_launch(void* const* d_in, const int* in_sizes, int n_in,
                              void* d_out, int out_size, void* d_ws, size_t ws_size,
                              hipStream_t stream)
{
    const float* x = (const float*)d_in[0];
    const float* W = (const float*)d_in[1];
    const float* bias = (const float*)d_in[2];
    float* out = (float*)d_out;

    const size_t bw_bytes = (size_t)RG_TOT * 256 * 16;   // 16.78 MB

    char* Bw2 = (char*)d_ws;
    float* part = (float*)((char*)d_ws + bw_bytes);      // 67.1 MB (ws>=84MB proven R3)

    prep_w<<<4096, 256, 0, stream>>>((const float4v*)W, (uint4v*)Bw2);
    // 512 blocks x 256 thr; LDS 48KB -> 2 blocks/CU; ~220 regs -> 2 waves/SIMD
    kan_main<<<(BATCH / 256) * 2 * NC, THREADS, 0, stream>>>(x, Bw2, part);
    reduce_bias<<<(BATCH * ODIM / 4) / 256, 256, 0, stream>>>(
        (const float4v*)part, (const float4v*)bias, (float4v*)out);
}